// Round 4
// baseline (2253.728 us; speedup 1.0000x reference)
//
#include <hip/hip_runtime.h>
#include <hip/hip_bf16.h>

// MemoryLSTM: B=32, S=128, I=512, H=512, M=256, V=100000
// cvt_bf16:  Xb,Wb = bf16(X), bf16(W_ih)
// gemm_mfma: Gb[4096][2048](bf16) = Xb @ Wb^T + b_ih + b_hh   (MFMA 16x16x32)
// prep_prev: prev[t] = latest t'<t with tok[t']==tok[t] (else -1)
// lstm_pipe: 32 sentences x 8 WGs x 512 thr, all sentences concurrent.
//            W_hh slice bf16-packed register-resident (128 VGPR/thread).
//            Hierarchical h-exchange: waves 0-1 poll stamped slots -> LDS.
//            Block swizzle keeps each sentence's 8 WGs on one XCD.

#define T_TOTAL 4096
#define Ssz 128
#define HID 512
#define RDIM 2048
#define KDIM 512
#define MSZ 256
#define NX (1 << 21)   // X elements (32*128*512)

typedef unsigned long long u64;
typedef unsigned int u32;
typedef unsigned short u16;
typedef __attribute__((ext_vector_type(8))) short bf16x8;
typedef __attribute__((ext_vector_type(4))) float f32x4;

__device__ __forceinline__ u16 f2bf(float x) {
  u32 u = __float_as_uint(x);
  u32 r = (u + 0x7fffu + ((u >> 16) & 1u)) >> 16;   // round-nearest-even
  return (u16)r;
}
__device__ __forceinline__ float bf2f(u16 b) {
  return __uint_as_float(((u32)b) << 16);
}

// ---------------- fp32 -> bf16 convert (X ++ W_ih) ----------------
__global__ __launch_bounds__(256) void cvt_bf16(
    const float* __restrict__ X, const float* __restrict__ W,
    u16* __restrict__ dst)   // Xb ++ Wb contiguous
{
  const int i = (blockIdx.x * 256 + threadIdx.x) * 4;
  const float* s = (i < NX) ? &X[i] : &W[i - NX];
  const float4 v = *(const float4*)s;
  ushort4 o;
  o.x = f2bf(v.x); o.y = f2bf(v.y); o.z = f2bf(v.z); o.w = f2bf(v.w);
  *(ushort4*)&dst[i] = o;
}

// ---------------- Gb = bf16(Xb @ Wb^T + b_ih + b_hh), MFMA ----------------
__global__ __launch_bounds__(256) void gemm_mfma(
    const u16* __restrict__ Xb, const u16* __restrict__ Wb,
    const float* __restrict__ b_ih, const float* __restrict__ b_hh,
    u16* __restrict__ Gb)
{
  const int tid = threadIdx.x;
  const int wave = tid >> 6;            // 0..3 -> 2x2 wave grid
  const int lane = tid & 63;
  const int wm = wave >> 1, wn = wave & 1;
  const int m0 = blockIdx.x * 64 + wm * 32;
  const int n0 = blockIdx.y * 64 + wn * 32;
  const int fr = lane & 15;             // fragment row/col
  const int kc = lane >> 4;             // k-chunk 0..3 (8 elems each)

  f32x4 acc[2][2] = {};
  const u16* ax0 = &Xb[(size_t)(m0 + fr) * KDIM + kc * 8];
  const u16* ax1 = ax0 + 16 * KDIM;
  const u16* bx0 = &Wb[(size_t)(n0 + fr) * KDIM + kc * 8];
  const u16* bx1 = bx0 + 16 * KDIM;
#pragma unroll
  for (int k0 = 0; k0 < KDIM; k0 += 32) {
    const bf16x8 a0 = *(const bf16x8*)(ax0 + k0);
    const bf16x8 a1 = *(const bf16x8*)(ax1 + k0);
    const bf16x8 b0 = *(const bf16x8*)(bx0 + k0);
    const bf16x8 b1 = *(const bf16x8*)(bx1 + k0);
    acc[0][0] = __builtin_amdgcn_mfma_f32_16x16x32_bf16(a0, b0, acc[0][0], 0, 0, 0);
    acc[0][1] = __builtin_amdgcn_mfma_f32_16x16x32_bf16(a0, b1, acc[0][1], 0, 0, 0);
    acc[1][0] = __builtin_amdgcn_mfma_f32_16x16x32_bf16(a1, b0, acc[1][0], 0, 0, 0);
    acc[1][1] = __builtin_amdgcn_mfma_f32_16x16x32_bf16(a1, b1, acc[1][1], 0, 0, 0);
  }
#pragma unroll
  for (int j = 0; j < 2; ++j) {
    const int col = n0 + j * 16 + fr;
    const float bb = b_ih[col] + b_hh[col];
#pragma unroll
    for (int i = 0; i < 2; ++i) {
#pragma unroll
      for (int r = 0; r < 4; ++r) {
        const int row = m0 + i * 16 + kc * 4 + r;   // D: col=lane&15, row=(lane>>4)*4+r
        Gb[(size_t)row * RDIM + col] = f2bf(acc[i][j][r] + bb);
      }
    }
  }
}

// ---------------- dependency precompute ----------------
__global__ __launch_bounds__(256) void prep_prev(
    const int* __restrict__ tok, int* __restrict__ prev)
{
  __shared__ int tl[T_TOTAL];
  for (int i = threadIdx.x; i < T_TOTAL; i += 256) tl[i] = tok[i];
  __syncthreads();
  const int t = blockIdx.x * 256 + threadIdx.x;
  const int my = tl[t];
  int p = -1;
  for (int u = t - 1; u >= 0; --u)
    if (tl[u] == my) { p = u; break; }
  prev[t] = p;
}

// ---------------- pipelined recurrence ----------------
__global__ __launch_bounds__(512, 2) void lstm_pipe(
    const u16* __restrict__ Gb, const float* __restrict__ Whh,
    const int* __restrict__ prev,
    u64* __restrict__ mbox,    // [4096][256] stamped c-slices (write-once)
    u64* __restrict__ hslot,   // [32][2][512] stamped h, parity double-buffered
    float* __restrict__ hs, float* __restrict__ last)
{
  const int bid = blockIdx.x;
  const int g  = bid & 31;       // sentence; bid%8 invariant per sentence -> same XCD
  const int wl = bid >> 5;       // local WG 0..7: owns hidden [wl*64, wl*64+64)
  const int tid = threadIdx.x;   // 0..511
  const int r = tid >> 1;        // 0..255: local gate row = gg*64 + jj
  const int q = tid & 1;         // half of the 512 cols
  const int gg = r >> 6;
  const int jj = r & 63;
  const int grow = gg * HID + wl * 64 + jj;   // global gate row

  __shared__ float h_l[HID];
  __shared__ float gsum[256];

  // bf16-packed W_hh slice: row grow, cols [q*256, q*256+256) -> 128 u32
  u32 wreg[128];
  {
    const float* wrow = &Whh[(size_t)grow * KDIM + q * 256];
#pragma unroll
    for (int k = 0; k < 32; ++k) {
      const float4 w0 = *(const float4*)&wrow[k * 8];
      const float4 w1 = *(const float4*)&wrow[k * 8 + 4];
      wreg[k * 4 + 0] = (u32)f2bf(w0.x) | ((u32)f2bf(w0.y) << 16);
      wreg[k * 4 + 1] = (u32)f2bf(w0.z) | ((u32)f2bf(w0.w) << 16);
      wreg[k * 4 + 2] = (u32)f2bf(w1.x) | ((u32)f2bf(w1.y) << 16);
      wreg[k * 4 + 3] = (u32)f2bf(w1.z) | ((u32)f2bf(w1.w) << 16);
    }
  }

  u64* hsl = hslot + ((size_t)g << 10);   // this group's [2][512]
  const int j = wl * 64 + tid;            // hidden unit (valid tid<64)
  const int mcol = (wl - 4) * 64 + tid;   // memory col (valid wl>=4, tid<64)

  float c_reg = 0.f;

  for (int s = 0; s < Ssz; ++s) {
    const int t = g * Ssz + s;

    // ---- early issues (overlap with h poll) ----
    float gv = 0.f;
    if (q == 0) gv = bf2f(Gb[(size_t)t * RDIM + grow]);
    int pt = -1; u64 mv = 0;
    if (wl >= 4 && tid < 64) {
      pt = prev[t];
      if (pt >= 0)
        mv = __hip_atomic_load(&mbox[(size_t)pt * MSZ + mcol],
                               __ATOMIC_RELAXED, __HIP_MEMORY_SCOPE_AGENT);
    }

    // ---- obtain h_{s-1}: waves 0-1 poll foreign chunks, stage to LDS ----
    if (s == 0) {
      h_l[tid] = 0.f;
    } else if (tid < 128) {
      const int half = tid >> 6;       // chunks [half*4, half*4+4)
      const int ln = tid & 63;
      u64* base = &hsl[(s & 1) << 9];
      u32 pend = 0xfu;
      if ((wl >> 2) == half) pend &= ~(1u << (wl & 3));   // skip own chunk
      while (pend) {
        u64 v[4];
#pragma unroll
        for (int c = 0; c < 4; ++c)
          if (pend & (1u << c))
            v[c] = __hip_atomic_load(&base[(half * 4 + c) * 64 + ln],
                                     __ATOMIC_RELAXED, __HIP_MEMORY_SCOPE_AGENT);
#pragma unroll
        for (int c = 0; c < 4; ++c)
          if ((pend & (1u << c)) && (u32)(v[c] >> 32) == (u32)s) {
            h_l[(half * 4 + c) * 64 + ln] = __uint_as_float((u32)v[c]);
            pend &= ~(1u << c);
          }
        if (pend) __builtin_amdgcn_s_sleep(1);
      }
    }
    __syncthreads();

    // ---- gate dot: 256 cols/thread, weights in registers ----
    float p = 0.f;
    const float* hb = &h_l[q * 256];
#pragma unroll
    for (int k = 0; k < 64; ++k) {
      const float4 h4 = *(const float4*)&hb[k * 4];
      const u32 wa = wreg[k * 2], wb = wreg[k * 2 + 1];
      p += __uint_as_float(wa << 16) * h4.x;
      p += __uint_as_float(wa & 0xffff0000u) * h4.y;
      p += __uint_as_float(wb << 16) * h4.z;
      p += __uint_as_float(wb & 0xffff0000u) * h4.w;
    }
    p += __shfl_xor(p, 1, 64);
    if (q == 0) gsum[r] = p + gv;
    __syncthreads();

    // ---- LSTM cell: one thread per hidden unit ----
    if (tid < 64) {
      const float zi = gsum[tid];
      const float zf = gsum[64 + tid];
      const float zg = gsum[128 + tid];
      const float zo = gsum[192 + tid];
      const float i_ = 1.f / (1.f + __expf(-zi));
      const float f_ = 1.f / (1.f + __expf(-zf));
      const float g_ = tanhf(zg);
      const float o_ = 1.f / (1.f + __expf(-zo));
      float cv;
      if (wl >= 4) {                       // spliced from memory chain
        if (pt >= 0) {
          while (!(u32)(mv >> 32)) {
            __builtin_amdgcn_s_sleep(2);
            mv = __hip_atomic_load(&mbox[(size_t)pt * MSZ + mcol],
                                   __ATOMIC_RELAXED, __HIP_MEMORY_SCOPE_AGENT);
          }
          cv = __uint_as_float((u32)mv);
        } else {
          cv = 0.f;                        // initial memory = zeros
        }
      } else {                             // persistent cell, reset per sentence
        cv = (s == 0) ? 0.f : c_reg;
      }
      const float c2 = f_ * cv + i_ * g_;
      const float h2 = o_ * tanhf(c2);
      c_reg = c2;

      // publish h for step s (stamp s+1, parity (s+1)&1); own chunk direct to LDS
      const u64 hp = ((u64)(u32)(s + 1) << 32) | (u64)__float_as_uint(h2);
      __hip_atomic_store(&hsl[(((s + 1) & 1) << 9) + j], hp,
                         __ATOMIC_RELAXED, __HIP_MEMORY_SCOPE_AGENT);
      h_l[j] = h2;
      if (wl >= 4) {                       // publish memory slice (write-once)
        const u64 mp = (1ull << 32) | (u64)__float_as_uint(c2);
        __hip_atomic_store(&mbox[(size_t)t * MSZ + mcol], mp,
                           __ATOMIC_RELAXED, __HIP_MEMORY_SCOPE_AGENT);
      }
      hs[(size_t)t * HID + j] = h2;
      if (s == Ssz - 1) last[(size_t)g * HID + j] = h2;
    }
  }
}

extern "C" void kernel_launch(void* const* d_in, const int* in_sizes, int n_in,
                              void* d_out, int out_size, void* d_ws, size_t ws_size,
                              hipStream_t stream) {
  const float* x     = (const float*)d_in[0];  // [32,128,512]
  const int*   tok   = (const int*)d_in[1];    // [32,128]
  const float* W_ih  = (const float*)d_in[2];  // [2048,512]
  const float* W_hh  = (const float*)d_in[3];  // [2048,512]
  const float* b_ih  = (const float*)d_in[4];  // [2048]
  const float* b_hh  = (const float*)d_in[5];  // [2048]
  float*       out   = (float*)d_out;          // hs (4096*512) ++ last (32*512)

  char* ws = (char*)d_ws;
  u64* mbox  = (u64*)ws;                               // 8 MB
  u64* hslot = (u64*)(ws + 8388608);                   // 256 KB
  int* prev  = (int*)(ws + 8650752);                   // 16 KB
  u16* XbWb  = (u16*)(ws + 8667136);                   // Xb 4 MB ++ Wb 2 MB
  u16* Xb    = XbWb;
  u16* Wb    = XbWb + NX;
  u16* Gb    = (u16*)(ws + 14958592);                  // 16.75 MB  (total ~30.3 MB)

  // zero mailbox stamps + h-slot stamps (ws re-poisoned each launch)
  hipMemsetAsync(d_ws, 0, 8650752, stream);

  cvt_bf16<<<(NX + (1 << 20)) / 1024, 256, 0, stream>>>(x, W_ih, XbWb);
  prep_prev<<<T_TOTAL / 256, 256, 0, stream>>>(tok, prev);
  gemm_mfma<<<dim3(T_TOTAL / 64, RDIM / 64), 256, 0, stream>>>(Xb, Wb, b_ih, b_hh, Gb);
  lstm_pipe<<<256, 512, 0, stream>>>(Gb, W_hh, prev, mbox, hslot,
                                     out, out + (size_t)T_TOTAL * HID);
}

// Round 5
// 2073.957 us; speedup vs baseline: 1.0867x; 1.0867x over previous
//
#include <hip/hip_runtime.h>
#include <hip/hip_bf16.h>

// MemoryLSTM: B=32, S=128, I=512, H=512, M=256, V=100000
// cvt_bf16:  Xb,Wb = bf16(X), bf16(W_ih)
// gemm_mfma: Gb[4096][2048](bf16) = Xb @ Wb^T + b_ih + b_hh   (MFMA 16x16x32)
// prep_prev: prev[t] = latest t'<t with tok[t']==tok[t] (else -1)
// lstm_pipe: 32 sentences x 8 WGs x 512 thr, all sentences concurrent.
//            W_hh slice bf16-packed register-resident (128 VGPR/thread).
//            h/mbox exchange via PLAIN coalesced sc0+sc1 loads/stores of
//            stamped 8B words (no atomics -> no per-lane serialization).
//            Wave k stages chunk k (7 staging waves in parallel).

#define T_TOTAL 4096
#define Ssz 128
#define HID 512
#define RDIM 2048
#define KDIM 512
#define MSZ 256
#define NX (1 << 21)   // X elements (32*128*512)

typedef unsigned long long u64;
typedef unsigned int u32;
typedef unsigned short u16;
typedef __attribute__((ext_vector_type(8))) short bf16x8;
typedef __attribute__((ext_vector_type(4))) float f32x4;

__device__ __forceinline__ u16 f2bf(float x) {
  u32 u = __float_as_uint(x);
  u32 r = (u + 0x7fffu + ((u >> 16) & 1u)) >> 16;   // round-nearest-even
  return (u16)r;
}
__device__ __forceinline__ float bf2f(u16 b) {
  return __uint_as_float(((u32)b) << 16);
}

// Coherent (die-level) 8B load/store: bypass L1+L2 (sc0 sc1), coalescable,
// placement-independent. Stamp-in-word makes them self-validating, so no
// atomicity / fences / ordering needed beyond the single naturally-aligned op.
__device__ __forceinline__ u64 ld_cohere(const u64* p) {
  u64 v;
  asm volatile("global_load_dwordx2 %0, %1, off sc0 sc1\n\ts_waitcnt vmcnt(0)"
               : "=v"(v) : "v"(p) : "memory");
  return v;
}
__device__ __forceinline__ void st_cohere(u64* p, u64 v) {
  asm volatile("global_store_dwordx2 %0, %1, off sc0 sc1"
               :: "v"(p), "v"(v) : "memory");
}

// ---------------- fp32 -> bf16 convert (X ++ W_ih) ----------------
__global__ __launch_bounds__(256) void cvt_bf16(
    const float* __restrict__ X, const float* __restrict__ W,
    u16* __restrict__ dst)   // Xb ++ Wb contiguous
{
  const int i = (blockIdx.x * 256 + threadIdx.x) * 4;
  const float* s = (i < NX) ? &X[i] : &W[i - NX];
  const float4 v = *(const float4*)s;
  ushort4 o;
  o.x = f2bf(v.x); o.y = f2bf(v.y); o.z = f2bf(v.z); o.w = f2bf(v.w);
  *(ushort4*)&dst[i] = o;
}

// ---------------- Gb = bf16(Xb @ Wb^T + b_ih + b_hh), MFMA ----------------
__global__ __launch_bounds__(256) void gemm_mfma(
    const u16* __restrict__ Xb, const u16* __restrict__ Wb,
    const float* __restrict__ b_ih, const float* __restrict__ b_hh,
    u16* __restrict__ Gb)
{
  const int tid = threadIdx.x;
  const int wave = tid >> 6;            // 0..3 -> 2x2 wave grid
  const int lane = tid & 63;
  const int wm = wave >> 1, wn = wave & 1;
  const int m0 = blockIdx.x * 64 + wm * 32;
  const int n0 = blockIdx.y * 64 + wn * 32;
  const int fr = lane & 15;             // fragment row/col
  const int kc = lane >> 4;             // k-chunk 0..3 (8 elems each)

  f32x4 acc[2][2] = {};
  const u16* ax0 = &Xb[(size_t)(m0 + fr) * KDIM + kc * 8];
  const u16* ax1 = ax0 + 16 * KDIM;
  const u16* bx0 = &Wb[(size_t)(n0 + fr) * KDIM + kc * 8];
  const u16* bx1 = bx0 + 16 * KDIM;
#pragma unroll
  for (int k0 = 0; k0 < KDIM; k0 += 32) {
    const bf16x8 a0 = *(const bf16x8*)(ax0 + k0);
    const bf16x8 a1 = *(const bf16x8*)(ax1 + k0);
    const bf16x8 b0 = *(const bf16x8*)(bx0 + k0);
    const bf16x8 b1 = *(const bf16x8*)(bx1 + k0);
    acc[0][0] = __builtin_amdgcn_mfma_f32_16x16x32_bf16(a0, b0, acc[0][0], 0, 0, 0);
    acc[0][1] = __builtin_amdgcn_mfma_f32_16x16x32_bf16(a0, b1, acc[0][1], 0, 0, 0);
    acc[1][0] = __builtin_amdgcn_mfma_f32_16x16x32_bf16(a1, b0, acc[1][0], 0, 0, 0);
    acc[1][1] = __builtin_amdgcn_mfma_f32_16x16x32_bf16(a1, b1, acc[1][1], 0, 0, 0);
  }
#pragma unroll
  for (int jn = 0; jn < 2; ++jn) {
    const int col = n0 + jn * 16 + fr;
    const float bb = b_ih[col] + b_hh[col];
#pragma unroll
    for (int i = 0; i < 2; ++i) {
#pragma unroll
      for (int rr = 0; rr < 4; ++rr) {
        const int row = m0 + i * 16 + kc * 4 + rr;  // D: col=lane&15, row=(lane>>4)*4+rr
        Gb[(size_t)row * RDIM + col] = f2bf(acc[i][jn][rr] + bb);
      }
    }
  }
}

// ---------------- dependency precompute ----------------
__global__ __launch_bounds__(256) void prep_prev(
    const int* __restrict__ tok, int* __restrict__ prev)
{
  __shared__ int tl[T_TOTAL];
  for (int i = threadIdx.x; i < T_TOTAL; i += 256) tl[i] = tok[i];
  __syncthreads();
  const int t = blockIdx.x * 256 + threadIdx.x;
  const int my = tl[t];
  int p = -1;
  for (int u = t - 1; u >= 0; --u)
    if (tl[u] == my) { p = u; break; }
  prev[t] = p;
}

// ---------------- pipelined recurrence ----------------
__global__ __launch_bounds__(512, 2) void lstm_pipe(
    const u16* __restrict__ Gb, const float* __restrict__ Whh,
    const int* __restrict__ prev,
    u64* __restrict__ mbox,    // [4096][256] stamped c-slices (write-once, stamp==1)
    u64* __restrict__ hslot,   // [32][2][512] stamped h (stamp==step), parity dbuf
    float* __restrict__ hs, float* __restrict__ last)
{
  const int bid = blockIdx.x;
  const int g  = bid & 31;       // sentence; bid%8 invariant -> same XCD (locality)
  const int wl = bid >> 5;       // local WG 0..7: owns hidden [wl*64, wl*64+64)
  const int tid = threadIdx.x;   // 0..511
  const int wv = tid >> 6;       // wave 0..7 (stages chunk wv)
  const int ln = tid & 63;
  const int r = tid >> 1;        // 0..255: local gate row = gg*64 + jj
  const int q = tid & 1;         // half of the 512 cols
  const int gg = r >> 6;
  const int jj = r & 63;
  const int grow = gg * HID + wl * 64 + jj;   // global gate row

  __shared__ float h_l[HID];
  __shared__ float gsum[256];

  // bf16-packed W_hh slice: row grow, cols [q*256, q*256+256) -> 128 u32
  u32 wreg[128];
  {
    const float* wrow = &Whh[(size_t)grow * KDIM + q * 256];
#pragma unroll
    for (int k = 0; k < 32; ++k) {
      const float4 w0 = *(const float4*)&wrow[k * 8];
      const float4 w1 = *(const float4*)&wrow[k * 8 + 4];
      wreg[k * 4 + 0] = (u32)f2bf(w0.x) | ((u32)f2bf(w0.y) << 16);
      wreg[k * 4 + 1] = (u32)f2bf(w0.z) | ((u32)f2bf(w0.w) << 16);
      wreg[k * 4 + 2] = (u32)f2bf(w1.x) | ((u32)f2bf(w1.y) << 16);
      wreg[k * 4 + 3] = (u32)f2bf(w1.z) | ((u32)f2bf(w1.w) << 16);
    }
  }

  u64* hsl = hslot + ((size_t)g << 10);   // this group's [2][512]
  const int j = wl * 64 + tid;            // hidden unit (valid tid<64)
  const int mcol = (wl - 4) * 64 + tid;   // memory col (valid wl>=4, tid<64)

  float c_reg = 0.f;

  for (int s = 0; s < Ssz; ++s) {
    const int t = g * Ssz + s;

    // ---- gate-bias prefetch (overlaps staging wait) ----
    float gv = 0.f;
    if (q == 0) gv = bf2f(Gb[(size_t)t * RDIM + grow]);

    // ---- stage h_{s-1}: wave wv bulk-loads chunk wv (own chunk already in LDS) ----
    if (s == 0) {
      h_l[tid] = 0.f;
    } else if (wv != wl) {
      u64* sp = &hsl[((s & 1) << 9) + wv * 64 + ln];
      u64 v = ld_cohere(sp);               // coalesced 64-lane sweep
      while (!__all((u32)(v >> 32) == (u32)s)) {
        __builtin_amdgcn_s_sleep(1);
        v = ld_cohere(sp);                 // idempotent: slot is write-once per window
      }
      h_l[wv * 64 + ln] = __uint_as_float((u32)v);
    }
    __syncthreads();

    // ---- gate dot: 256 cols/thread, weights in registers, 4 accumulators ----
    float p0 = 0.f, p1 = 0.f, p2 = 0.f, p3 = 0.f;
    const float* hb = &h_l[q * 256];
#pragma unroll
    for (int k = 0; k < 64; ++k) {
      const float4 h4 = *(const float4*)&hb[k * 4];
      const u32 wa = wreg[k * 2], wb = wreg[k * 2 + 1];
      p0 += __uint_as_float(wa << 16) * h4.x;
      p1 += __uint_as_float(wa & 0xffff0000u) * h4.y;
      p2 += __uint_as_float(wb << 16) * h4.z;
      p3 += __uint_as_float(wb & 0xffff0000u) * h4.w;
    }
    float p = (p0 + p1) + (p2 + p3);
    p += __shfl_xor(p, 1, 64);
    if (q == 0) gsum[r] = p + gv;
    __syncthreads();

    // ---- LSTM cell: wave 0, one lane per hidden unit ----
    if (tid < 64) {
      const float zi = gsum[tid];
      const float zf = gsum[64 + tid];
      const float zg = gsum[128 + tid];
      const float zo = gsum[192 + tid];
      const float i_ = 1.f / (1.f + __expf(-zi));
      const float f_ = 1.f / (1.f + __expf(-zf));
      const float g_ = tanhf(zg);
      const float o_ = 1.f / (1.f + __expf(-zo));
      float cv;
      if (wl >= 4) {                       // spliced from cross-sentence memory chain
        const int pt = prev[t];
        if (pt >= 0) {
          u64 mv = ld_cohere(&mbox[(size_t)pt * MSZ + mcol]);
          while ((u32)(mv >> 32) != 1u) {  // exact stamp: poison-safe, no memset
            __builtin_amdgcn_s_sleep(2);
            mv = ld_cohere(&mbox[(size_t)pt * MSZ + mcol]);
          }
          cv = __uint_as_float((u32)mv);
        } else {
          cv = 0.f;                        // initial memory = zeros
        }
      } else {                             // persistent cell, reset per sentence
        cv = (s == 0) ? 0.f : c_reg;
      }
      const float c2 = f_ * cv + i_ * g_;
      const float h2 = o_ * tanhf(c2);
      c_reg = c2;

      // publish h (stamp s+1, parity (s+1)&1): ONE coalesced plain store
      st_cohere(&hsl[(((s + 1) & 1) << 9) + j],
                ((u64)(u32)(s + 1) << 32) | (u64)__float_as_uint(h2));
      h_l[j] = h2;                         // own chunk for next step (LDS)
      if (wl >= 4)                         // publish memory slice (write-once)
        st_cohere(&mbox[(size_t)t * MSZ + mcol],
                  (1ull << 32) | (u64)__float_as_uint(c2));
      hs[(size_t)t * HID + j] = h2;
      if (s == Ssz - 1) last[(size_t)g * HID + j] = h2;
    }
  }
}

extern "C" void kernel_launch(void* const* d_in, const int* in_sizes, int n_in,
                              void* d_out, int out_size, void* d_ws, size_t ws_size,
                              hipStream_t stream) {
  const float* x     = (const float*)d_in[0];  // [32,128,512]
  const int*   tok   = (const int*)d_in[1];    // [32,128]
  const float* W_ih  = (const float*)d_in[2];  // [2048,512]
  const float* W_hh  = (const float*)d_in[3];  // [2048,512]
  const float* b_ih  = (const float*)d_in[4];  // [2048]
  const float* b_hh  = (const float*)d_in[5];  // [2048]
  float*       out   = (float*)d_out;          // hs (4096*512) ++ last (32*512)

  char* ws = (char*)d_ws;
  u64* mbox  = (u64*)ws;                               // 8 MB
  u64* hslot = (u64*)(ws + 8388608);                   // 256 KB
  int* prev  = (int*)(ws + 8650752);                   // 16 KB
  u16* XbWb  = (u16*)(ws + 8667136);                   // Xb 4 MB ++ Wb 2 MB
  u16* Xb    = XbWb;
  u16* Wb    = XbWb + NX;
  u16* Gb    = (u16*)(ws + 14958592);                  // 16.75 MB  (total ~30.3 MB)

  // No memset needed: hslot stamps validated by exact step number, mbox by ==1;
  // the 0xAA poison (0xAAAAAAAA) can never match either.

  cvt_bf16<<<(NX + (1 << 20)) / 1024, 256, 0, stream>>>(x, W_ih, XbWb);
  prep_prev<<<T_TOTAL / 256, 256, 0, stream>>>(tok, prev);
  gemm_mfma<<<dim3(T_TOTAL / 64, RDIM / 64), 256, 0, stream>>>(Xb, Wb, b_ih, b_hh, Gb);
  lstm_pipe<<<256, 512, 0, stream>>>(Gb, W_hh, prev, mbox, hslot,
                                     out, out + (size_t)T_TOTAL * HID);
}

// Round 6
// 1156.293 us; speedup vs baseline: 1.9491x; 1.7936x over previous
//
#include <hip/hip_runtime.h>
#include <hip/hip_bf16.h>

// MemoryLSTM: B=32, S=128, I=512, H=512, M=256, V=100000
// cvt_bf16:  Xb,Wb = bf16(X), bf16(W_ih)
// gemm_mfma: Gb[4096][2048](bf16) = Xb @ Wb^T + b_ih + b_hh   (MFMA 16x16x32)
// prep_prev: prev[t] = latest t'<t with tok[t']==tok[t] (else -1)
// lstm_pipe: 32 sentences x 8 WGs x 512 thr, all sentences concurrent.
//            Recurrent GEMV via MFMA (N=1, col 0): W_hh A-fragments
//            register-resident (128 VGPR/thread); h enters as bf16+residual
//            (two MFMAs -> f32-h-equivalent precision). LDS dot traffic
//            drops ~500x vs VALU dot (the measured 2^26-conflict bottleneck).
//            h/mbox exchange via coalesced sc0+sc1 stamped 8B words.

#define T_TOTAL 4096
#define Ssz 128
#define HID 512
#define RDIM 2048
#define KDIM 512
#define MSZ 256
#define NX (1 << 21)   // X elements (32*128*512)

typedef unsigned long long u64;
typedef unsigned int u32;
typedef unsigned short u16;
typedef __attribute__((ext_vector_type(8))) short bf16x8;
typedef __attribute__((ext_vector_type(4))) float f32x4;

__device__ __forceinline__ u16 f2bf(float x) {
  u32 u = __float_as_uint(x);
  u32 r = (u + 0x7fffu + ((u >> 16) & 1u)) >> 16;   // round-nearest-even
  return (u16)r;
}
__device__ __forceinline__ float bf2f(u16 b) {
  return __uint_as_float(((u32)b) << 16);
}

// Coherent (die-level) 8B load/store: bypass L1+L2 (sc0 sc1), coalescable.
// Stamp-in-word makes them self-validating (no atomicity/fences needed).
__device__ __forceinline__ u64 ld_cohere(const u64* p) {
  u64 v;
  asm volatile("global_load_dwordx2 %0, %1, off sc0 sc1\n\ts_waitcnt vmcnt(0)"
               : "=v"(v) : "v"(p) : "memory");
  return v;
}
__device__ __forceinline__ void st_cohere(u64* p, u64 v) {
  asm volatile("global_store_dwordx2 %0, %1, off sc0 sc1"
               :: "v"(p), "v"(v) : "memory");
}

// ---------------- fp32 -> bf16 convert (X ++ W_ih) ----------------
__global__ __launch_bounds__(256) void cvt_bf16(
    const float* __restrict__ X, const float* __restrict__ W,
    u16* __restrict__ dst)
{
  const int i = (blockIdx.x * 256 + threadIdx.x) * 4;
  const float* s = (i < NX) ? &X[i] : &W[i - NX];
  const float4 v = *(const float4*)s;
  ushort4 o;
  o.x = f2bf(v.x); o.y = f2bf(v.y); o.z = f2bf(v.z); o.w = f2bf(v.w);
  *(ushort4*)&dst[i] = o;
}

// ---------------- Gb = bf16(Xb @ Wb^T + b_ih + b_hh), MFMA ----------------
__global__ __launch_bounds__(256) void gemm_mfma(
    const u16* __restrict__ Xb, const u16* __restrict__ Wb,
    const float* __restrict__ b_ih, const float* __restrict__ b_hh,
    u16* __restrict__ Gb)
{
  const int tid = threadIdx.x;
  const int wave = tid >> 6;
  const int lane = tid & 63;
  const int wm = wave >> 1, wn = wave & 1;
  const int m0 = blockIdx.x * 64 + wm * 32;
  const int n0 = blockIdx.y * 64 + wn * 32;
  const int fr = lane & 15;
  const int kc = lane >> 4;

  f32x4 acc[2][2] = {};
  const u16* ax0 = &Xb[(size_t)(m0 + fr) * KDIM + kc * 8];
  const u16* ax1 = ax0 + 16 * KDIM;
  const u16* bx0 = &Wb[(size_t)(n0 + fr) * KDIM + kc * 8];
  const u16* bx1 = bx0 + 16 * KDIM;
#pragma unroll
  for (int k0 = 0; k0 < KDIM; k0 += 32) {
    const bf16x8 a0 = *(const bf16x8*)(ax0 + k0);
    const bf16x8 a1 = *(const bf16x8*)(ax1 + k0);
    const bf16x8 b0 = *(const bf16x8*)(bx0 + k0);
    const bf16x8 b1 = *(const bf16x8*)(bx1 + k0);
    acc[0][0] = __builtin_amdgcn_mfma_f32_16x16x32_bf16(a0, b0, acc[0][0], 0, 0, 0);
    acc[0][1] = __builtin_amdgcn_mfma_f32_16x16x32_bf16(a0, b1, acc[0][1], 0, 0, 0);
    acc[1][0] = __builtin_amdgcn_mfma_f32_16x16x32_bf16(a1, b0, acc[1][0], 0, 0, 0);
    acc[1][1] = __builtin_amdgcn_mfma_f32_16x16x32_bf16(a1, b1, acc[1][1], 0, 0, 0);
  }
#pragma unroll
  for (int jn = 0; jn < 2; ++jn) {
    const int col = n0 + jn * 16 + fr;
    const float bb = b_ih[col] + b_hh[col];
#pragma unroll
    for (int i = 0; i < 2; ++i) {
#pragma unroll
      for (int rr = 0; rr < 4; ++rr) {
        const int row = m0 + i * 16 + kc * 4 + rr;
        Gb[(size_t)row * RDIM + col] = f2bf(acc[i][jn][rr] + bb);
      }
    }
  }
}

// ---------------- dependency precompute ----------------
__global__ __launch_bounds__(256) void prep_prev(
    const int* __restrict__ tok, int* __restrict__ prev)
{
  __shared__ int tl[T_TOTAL];
  for (int i = threadIdx.x; i < T_TOTAL; i += 256) tl[i] = tok[i];
  __syncthreads();
  const int t = blockIdx.x * 256 + threadIdx.x;
  const int my = tl[t];
  int p = -1;
  for (int u = t - 1; u >= 0; --u)
    if (tl[u] == my) { p = u; break; }
  prev[t] = p;
}

// ---------------- pipelined recurrence (MFMA GEMV) ----------------
__global__ __launch_bounds__(512, 2) void lstm_pipe(
    const u16* __restrict__ Gb, const float* __restrict__ Whh,
    const int* __restrict__ prev,
    u64* __restrict__ mbox,    // [4096][256] stamped c-slices (stamp==1)
    u64* __restrict__ hslot,   // [32][2][512] stamped h (stamp==step), parity dbuf
    float* __restrict__ hs, float* __restrict__ last)
{
  const int bid = blockIdx.x;
  const int g  = bid & 31;       // sentence; bid%8 invariant -> same XCD
  const int wl = bid >> 5;       // local WG 0..7: owns hidden [wl*64, wl*64+64)
  const int tid = threadIdx.x;   // 0..511
  const int wv = tid >> 6;       // wave 0..7
  const int ln = tid & 63;
  const int fr = ln & 15;        // MFMA fragment row (M) / output col (N)
  const int kb = ln >> 4;        // k-subblock 0..3 (8 elems each)

  __shared__ u16 hb16[HID];      // h as bf16
  __shared__ u16 hr16[HID];      // residual (h - bf16(h)) as bf16
  __shared__ float gsum[256];

  // A-fragments: wave wv owns row-blocks rb = 2wv, 2wv+1 (16 rows each),
  // 16 k-chunks of 32. Lane holds A[fr][kc*32 + kb*8 .. +8] as bf16x8.
  bf16x8 areg[2][16];
#pragma unroll
  for (int b = 0; b < 2; ++b) {
    const int rb = wv * 2 + b;
    const int gg = rb >> 2, jb = rb & 3;
    const int grow = gg * HID + wl * 64 + jb * 16 + fr;
#pragma unroll
    for (int kc = 0; kc < 16; ++kc) {
      const float* src = &Whh[(size_t)grow * KDIM + kc * 32 + kb * 8];
      const float4 f0 = *(const float4*)src;
      const float4 f1 = *(const float4*)(src + 4);
      union { bf16x8 v; u32 u[4]; } pk;
      pk.u[0] = (u32)f2bf(f0.x) | ((u32)f2bf(f0.y) << 16);
      pk.u[1] = (u32)f2bf(f0.z) | ((u32)f2bf(f0.w) << 16);
      pk.u[2] = (u32)f2bf(f1.x) | ((u32)f2bf(f1.y) << 16);
      pk.u[3] = (u32)f2bf(f1.z) | ((u32)f2bf(f1.w) << 16);
      areg[b][kc] = pk.v;
    }
  }

  u64* hsl = hslot + ((size_t)g << 10);   // this group's [2][512]
  const int j = wl * 64 + tid;            // hidden unit (valid tid<64)
  const int mcol = (wl - 4) * 64 + tid;   // memory col (valid wl>=4, tid<64)

  float c_reg = 0.f;
  bf16x8 bzero = {};

  for (int s = 0; s < Ssz; ++s) {
    const int t = g * Ssz + s;

    // ---- early issues: G row + memory-chain first probe (hidden under poll) ----
    u16 g0 = 0, g1 = 0, g2 = 0, g3 = 0;
    int pt = -1; u64 mv = 0;
    if (tid < 64) {
      const u16* gr = &Gb[(size_t)t * RDIM + wl * 64 + tid];
      g0 = gr[0]; g1 = gr[512]; g2 = gr[1024]; g3 = gr[1536];
      if (wl >= 4) {
        pt = prev[t];
        if (pt >= 0)
          mv = ld_cohere(&mbox[(size_t)pt * MSZ + mcol]);
      }
    }

    // ---- stage h_{s-1}: wave wv polls chunk wv, writes bf16 + residual ----
    if (s == 0) {
      hb16[wv * 64 + ln] = 0; hr16[wv * 64 + ln] = 0;
    } else if (wv != wl) {       // own chunk written by cell at end of s-1
      u64* sp = &hsl[((s & 1) << 9) + wv * 64 + ln];
      u64 v = ld_cohere(sp);
      while (!__all((u32)(v >> 32) == (u32)s)) {
        __builtin_amdgcn_s_sleep(1);
        v = ld_cohere(sp);
      }
      const float hv = __uint_as_float((u32)v);
      const u16 h1 = f2bf(hv);
      hb16[wv * 64 + ln] = h1;
      hr16[wv * 64 + ln] = f2bf(hv - bf2f(h1));
    }
    __syncthreads();

    // ---- GEMV via MFMA: 2 row-blocks x 16 kc x (h1 + residual) ----
    f32x4 acc0 = {}, acc1 = {};
    bf16x8 b1 = bzero, br = bzero;
#pragma unroll
    for (int kc = 0; kc < 16; ++kc) {
      if (fr == 0) {             // only col-0 B lanes carry real h
        b1 = *(const bf16x8*)&hb16[kc * 32 + kb * 8];
        br = *(const bf16x8*)&hr16[kc * 32 + kb * 8];
      }
      acc0 = __builtin_amdgcn_mfma_f32_16x16x32_bf16(areg[0][kc], b1, acc0, 0, 0, 0);
      acc1 = __builtin_amdgcn_mfma_f32_16x16x32_bf16(areg[1][kc], b1, acc1, 0, 0, 0);
      acc0 = __builtin_amdgcn_mfma_f32_16x16x32_bf16(areg[0][kc], br, acc0, 0, 0, 0);
      acc1 = __builtin_amdgcn_mfma_f32_16x16x32_bf16(areg[1][kc], br, acc1, 0, 0, 0);
    }
    if (fr == 0) {               // D col 0: lanes 0,16,32,48; rows kb*4+r
      *(f32x4*)&gsum[(wv * 2 + 0) * 16 + kb * 4] = acc0;
      *(f32x4*)&gsum[(wv * 2 + 1) * 16 + kb * 4] = acc1;
    }
    __syncthreads();

    // ---- LSTM cell: wave 0, one lane per hidden unit ----
    if (tid < 64) {
      const float zi = gsum[tid]       + bf2f(g0);
      const float zf = gsum[64 + tid]  + bf2f(g1);
      const float zg = gsum[128 + tid] + bf2f(g2);
      const float zo = gsum[192 + tid] + bf2f(g3);
      const float i_ = 1.f / (1.f + __expf(-zi));
      const float f_ = 1.f / (1.f + __expf(-zf));
      const float g_ = tanhf(zg);
      const float o_ = 1.f / (1.f + __expf(-zo));
      float cv;
      if (wl >= 4) {                       // spliced from cross-sentence chain
        if (pt >= 0) {
          while ((u32)(mv >> 32) != 1u) {
            __builtin_amdgcn_s_sleep(2);
            mv = ld_cohere(&mbox[(size_t)pt * MSZ + mcol]);
          }
          cv = __uint_as_float((u32)mv);
        } else {
          cv = 0.f;                        // initial memory = zeros
        }
      } else {                             // persistent cell, reset per sentence
        cv = (s == 0) ? 0.f : c_reg;
      }
      const float c2 = f_ * cv + i_ * g_;
      const float h2 = o_ * tanhf(c2);
      c_reg = c2;

      // publish h (stamp s+1, parity (s+1)&1): one coalesced store
      st_cohere(&hsl[(((s + 1) & 1) << 9) + j],
                ((u64)(u32)(s + 1) << 32) | (u64)__float_as_uint(h2));
      if (wl >= 4)                         // publish memory slice (write-once)
        st_cohere(&mbox[(size_t)t * MSZ + mcol],
                  (1ull << 32) | (u64)__float_as_uint(c2));
      // own chunk for next step's MFMA (bf16 + residual)
      const u16 h1o = f2bf(h2);
      hb16[j] = h1o;
      hr16[j] = f2bf(h2 - bf2f(h1o));
      hs[(size_t)t * HID + j] = h2;
      if (s == Ssz - 1) last[(size_t)g * HID + j] = h2;
    }
  }
}

extern "C" void kernel_launch(void* const* d_in, const int* in_sizes, int n_in,
                              void* d_out, int out_size, void* d_ws, size_t ws_size,
                              hipStream_t stream) {
  const float* x     = (const float*)d_in[0];  // [32,128,512]
  const int*   tok   = (const int*)d_in[1];    // [32,128]
  const float* W_ih  = (const float*)d_in[2];  // [2048,512]
  const float* W_hh  = (const float*)d_in[3];  // [2048,512]
  const float* b_ih  = (const float*)d_in[4];  // [2048]
  const float* b_hh  = (const float*)d_in[5];  // [2048]
  float*       out   = (float*)d_out;          // hs (4096*512) ++ last (32*512)

  char* ws = (char*)d_ws;
  u64* mbox  = (u64*)ws;                               // 8 MB
  u64* hslot = (u64*)(ws + 8388608);                   // 256 KB
  int* prev  = (int*)(ws + 8650752);                   // 16 KB
  u16* XbWb  = (u16*)(ws + 8667136);                   // Xb 4 MB ++ Wb 2 MB
  u16* Xb    = XbWb;
  u16* Wb    = XbWb + NX;
  u16* Gb    = (u16*)(ws + 14958592);                  // 16.75 MB  (total ~30.3 MB)

  // No memset: hslot stamps validated by exact step number, mbox by ==1;
  // the 0xAA poison (0xAAAAAAAA) can never match either.

  cvt_bf16<<<(NX + (1 << 20)) / 1024, 256, 0, stream>>>(x, W_ih, XbWb);
  prep_prev<<<T_TOTAL / 256, 256, 0, stream>>>(tok, prev);
  gemm_mfma<<<dim3(T_TOTAL / 64, RDIM / 64), 256, 0, stream>>>(Xb, Wb, b_ih, b_hh, Gb);
  lstm_pipe<<<256, 512, 0, stream>>>(Gb, W_hh, prev, mbox, hslot,
                                     out, out + (size_t)T_TOTAL * HID);
}